// Round 3
// baseline (244.346 us; speedup 1.0000x reference)
//
#include <hip/hip_runtime.h>
#include <math.h>

// Problem constants (fixed by the reference)
#define T_    1024      // B*S tokens
#define H_    512       // hidden
#define I_    1024      // intermediate
#define E_    64        // routed experts
#define K_    4         // top-k
#define NPAIR (T_*K_)   // 4096 routed (token,slot) pairs
#define NENT  (NPAIR + T_)  // + shared-expert entries at [NPAIR + t]

#define BM 128          // rows per work block
#define BN 64
#define BKS 64          // k-step (elements)
#define MAXWORK 160

typedef float  f32x4  __attribute__((ext_vector_type(4)));
typedef short  bf16x8 __attribute__((ext_vector_type(8)));

__device__ __forceinline__ ushort f2bf(float f) {
    uint u = __float_as_uint(f);
    u += 0x7fffu + ((u >> 16) & 1u);   // round-to-nearest-even
    return (ushort)(u >> 16);
}

__device__ __forceinline__ bf16x8 cvt8(f32x4 a, f32x4 b) {
    bf16x8 r;
    r[0] = (short)f2bf(a[0]); r[1] = (short)f2bf(a[1]);
    r[2] = (short)f2bf(a[2]); r[3] = (short)f2bf(a[3]);
    r[4] = (short)f2bf(b[0]); r[5] = (short)f2bf(b[1]);
    r[6] = (short)f2bf(b[2]); r[7] = (short)f2bf(b[3]);
    return r;
}

// async global->LDS, 16B per lane; dest = wave-uniform base + lane*16
__device__ __forceinline__ void gload16(const void* g, void* lds) {
    __builtin_amdgcn_global_load_lds(
        (const __attribute__((address_space(1))) unsigned int*)g,
        (__attribute__((address_space(3))) unsigned int*)lds, 16, 0, 0);
}

// ---------------------------------------------------------------------------
// x -> bf16 pre-pass (stage1 staging source)
// ---------------------------------------------------------------------------
__global__ __launch_bounds__(256) void x_cvt(const float* __restrict__ x,
                                             ushort* __restrict__ xb)
{
    const int i = blockIdx.x*256 + threadIdx.x;     // T_*H_/4 float4s
    float4 v = reinterpret_cast<const float4*>(x)[i];
    reinterpret_cast<ushort4*>(xb)[i] =
        make_ushort4(f2bf(v.x), f2bf(v.y), f2bf(v.z), f2bf(v.w));
}

// ---------------------------------------------------------------------------
// Router: one 64-thread block per token.
// ---------------------------------------------------------------------------
__global__ __launch_bounds__(64) void moe_router(
    const float* __restrict__ x, const float* __restrict__ rw,
    const float* __restrict__ rb, const float* __restrict__ eb,
    int* __restrict__ idx_out, float* __restrict__ gate_out)
{
    const int t = blockIdx.x;
    const int lane = threadIdx.x;  // 0..63
    __shared__ float xs[H_];
    __shared__ float lg[E_];
    __shared__ float bs[E_];
    for (int i = lane; i < H_; i += 64) xs[i] = x[(size_t)t*H_ + i];
    bs[lane] = eb[lane];
    __syncthreads();
    float acc = 0.f;
    const float* wrow = rw + (size_t)lane*H_;
    for (int k = 0; k < H_; k += 4) {
        float4 w4 = *reinterpret_cast<const float4*>(wrow + k);
        acc = fmaf(xs[k+0], w4.x, acc);
        acc = fmaf(xs[k+1], w4.y, acc);
        acc = fmaf(xs[k+2], w4.z, acc);
        acc = fmaf(xs[k+3], w4.w, acc);
    }
    lg[lane] = acc + rb[lane];
    __syncthreads();
    if (lane == 0) {
        unsigned long long used = 0ull;
        int sel[K_]; float orig[K_];
        for (int k = 0; k < K_; ++k) {
            float best = -INFINITY; int bi = 0;
            for (int e = 0; e < E_; ++e) {
                if (used & (1ull << e)) continue;
                float v = lg[e] + bs[e];
                if (v > best) { best = v; bi = e; }   // strict > : lowest idx on tie
            }
            used |= (1ull << bi);
            sel[k] = bi; orig[k] = lg[bi];
        }
        float s[K_]; float sum = 0.f;
        for (int k = 0; k < K_; ++k) { s[k] = 1.f/(1.f + __expf(-orig[k])); sum += s[k]; }
        sum = fmaxf(sum, 1e-12f);
        for (int k = 0; k < K_; ++k) {
            idx_out[t*K_ + k] = sel[k];
            gate_out[t*K_ + k] = s[k] / sum;
        }
    }
}

// ---------------------------------------------------------------------------
// Build per-expert token lists + flattened row-block work list (single block).
// ---------------------------------------------------------------------------
__global__ __launch_bounds__(256) void moe_build(
    const int* __restrict__ idx, const float* __restrict__ gates,
    int* __restrict__ cnts, int* __restrict__ offs,
    int* __restrict__ entry_token, float* __restrict__ entry_gate,
    int* __restrict__ pair_pos,
    int* __restrict__ blk_e, int* __restrict__ blk_ro, int* __restrict__ nwork)
{
    __shared__ int c[E_];
    __shared__ int run[E_];
    const int tid = threadIdx.x;
    if (tid < E_) c[tid] = 0;
    __syncthreads();
    for (int p = tid; p < NPAIR; p += 256) atomicAdd(&c[idx[p]], 1);
    __syncthreads();
    if (tid == 0) {
        int o = 0;
        for (int e = 0; e < E_; ++e) { run[e] = o; offs[e] = o; cnts[e] = c[e]; o += c[e]; }
        offs[E_] = NPAIR;   // shared-expert entries
        cnts[E_] = T_;
        int nb = 0;
        for (int e = 0; e <= E_; ++e) {
            int n = (e < E_) ? c[e] : T_;
            for (int ro = 0; ro < n; ro += BM) { blk_e[nb] = e; blk_ro[nb] = ro; ++nb; }
        }
        nwork[0] = nb;
    }
    __syncthreads();
    for (int p = tid; p < NPAIR; p += 256) {
        int e = idx[p];
        int pos = atomicAdd(&run[e], 1);
        entry_token[pos] = p / K_;
        entry_gate[pos]  = gates[p];
        pair_pos[p]      = pos;
    }
    for (int t = tid; t < T_; t += 256) {
        entry_token[NPAIR + t] = t;
        entry_gate[NPAIR + t]  = 1.0f;
    }
}

// ---------------------------------------------------------------------------
// Stage 1: h1 = silu(X w1^T + b1) * (X w3^T + b3) -> bf16
// gload_lds double-buffered staging. X: bf16 tile [128][64], 16B-chunk XOR
// swizzle. W1/W3: fp32 tile [128][64] (rows 0..63 = W1, 64..127 = W3), 32B
// XOR swizzle, converted to bf16 at fragment read. LDS = 96KB.
// ---------------------------------------------------------------------------
__global__ __launch_bounds__(512, 2) void moe_stage1(
    const ushort* __restrict__ xbf,
    const float* __restrict__ w1, const float* __restrict__ b1,
    const float* __restrict__ w3, const float* __restrict__ b3,
    const float* __restrict__ sw1, const float* __restrict__ sb1,
    const float* __restrict__ sw3, const float* __restrict__ sb3,
    const int* __restrict__ cnts, const int* __restrict__ offs,
    const int* __restrict__ entry_token,
    const int* __restrict__ blk_e, const int* __restrict__ blk_ro,
    const int* __restrict__ nwork,
    ushort* __restrict__ h1buf)
{
    const int w = blockIdx.x;
    if (w >= nwork[0]) return;
    const int e  = blk_e[w];
    const int ro = blk_ro[w];
    const int itile = blockIdx.y;   // 0..I_/BN-1
    const int n = cnts[e];
    const int off = offs[e];
    const int rows = min(BM, n - ro);
    const float* W1 = (e < E_) ? (w1 + (size_t)e*I_*H_) : sw1;
    const float* W3 = (e < E_) ? (w3 + (size_t)e*I_*H_) : sw3;
    const float* B1 = (e < E_) ? (b1 + (size_t)e*I_) : sb1;
    const float* B3 = (e < E_) ? (b3 + (size_t)e*I_) : sb3;

    __shared__ ushort XL[2][BM*BKS];      // 2 x 16KB
    __shared__ float  WL[2][2*BN*BKS];    // 2 x 32KB

    const int tid  = threadIdx.x;
    const int lane = tid & 63;
    const int wid  = tid >> 6;          // 0..7
    const int wm   = wid >> 1;          // 0..3
    const int wn   = wid & 1;           // 0..1
    const int l15  = lane & 15;
    const int lg   = lane >> 4;         // 0..3

    // --- K-invariant per-lane staging sources (pre-swizzled) ---
    // X: 16 issues of 1KB (8 rows x 128B); wave handles j = wid*2 + i.
    const ushort* xsrc[2];
    #pragma unroll
    for (int i = 0; i < 2; ++i) {
        const int j = wid*2 + i;
        const int r = j*8 + (lane >> 3);            // tile row (8-aligned group)
        const int tok = entry_token[off + ro + r];
        const int csw = ((lane & 7) ^ (r & 7)) << 3; // bf16 elems (16B chunk swz)
        xsrc[i] = xbf + (size_t)tok*H_ + csw;
    }
    // W: 32 issues of 1KB (4 rows x 256B); wave handles j = wid*4 + i.
    const float* wsrc[4];
    #pragma unroll
    for (int i = 0; i < 4; ++i) {
        const int j = wid*4 + i;
        const int rb = j*4 + (lane >> 4);           // 0..127 (W1 then W3)
        const float* base = (rb < BN) ? (W1 + (size_t)(itile*BN + rb)*H_)
                                      : (W3 + (size_t)(itile*BN + rb - BN)*H_);
        const int c16 = lane & 15;
        const int csw = ((((c16 >> 1) ^ (rb & 7)) << 3) + ((c16 & 1) << 2)); // floats
        wsrc[i] = base + csw;
    }

    f32x4 acc1[2][2] = {};
    f32x4 acc3[2][2] = {};

    #define STAGE1(t, buf)                                                       \
        do {                                                                     \
            const int kc_ = (t) * BKS;                                           \
            _Pragma("unroll")                                                    \
            for (int i_ = 0; i_ < 2; ++i_)                                       \
                gload16(xsrc[i_] + kc_, (char*)&XL[buf][0] + (wid*2 + i_)*1024); \
            _Pragma("unroll")                                                    \
            for (int i_ = 0; i_ < 4; ++i_)                                       \
                gload16(wsrc[i_] + kc_, (char*)&WL[buf][0] + (wid*4 + i_)*1024); \
        } while (0)

    STAGE1(0, 0);
    __syncthreads();                    // drains vmcnt(0): buf0 ready

    const int NT = H_ / BKS;            // 8
    for (int t = 0; t < NT; ++t) {
        const int cur = t & 1;
        if (t + 1 < NT) STAGE1(t + 1, cur ^ 1);
        asm volatile("" ::: "memory");  // keep issue order: stage first
        #pragma unroll
        for (int s = 0; s < 2; ++s) {
            bf16x8 a[2], bb1[2], bb3[2];
            #pragma unroll
            for (int f = 0; f < 2; ++f) {
                const int rr = wm*32 + f*16 + l15;
                a[f] = *reinterpret_cast<const bf16x8*>(
                    (const char*)&XL[cur][0] + rr*128 + ((((s<<2)|lg) ^ (rr&7)) << 4));
                const int rw = wn*32 + f*16 + l15;
                const char* p1 = (const char*)&WL[cur][0] + rw*256
                               + ((((s<<2)|lg) ^ (rw&7)) << 5);
                f32x4 u0 = *reinterpret_cast<const f32x4*>(p1);
                f32x4 u1 = *reinterpret_cast<const f32x4*>(p1 + 16);
                bb1[f] = cvt8(u0, u1);
                const char* p3 = p1 + BN*256;   // (rw+64)&7 == rw&7: same swizzle
                f32x4 v0 = *reinterpret_cast<const f32x4*>(p3);
                f32x4 v1 = *reinterpret_cast<const f32x4*>(p3 + 16);
                bb3[f] = cvt8(v0, v1);
            }
            #pragma unroll
            for (int fm = 0; fm < 2; ++fm) {
                #pragma unroll
                for (int fn = 0; fn < 2; ++fn) {
                    acc1[fm][fn] = __builtin_amdgcn_mfma_f32_16x16x32_bf16(a[fm], bb1[fn], acc1[fm][fn], 0, 0, 0);
                    acc3[fm][fn] = __builtin_amdgcn_mfma_f32_16x16x32_bf16(a[fm], bb3[fn], acc3[fm][fn], 0, 0, 0);
                }
            }
        }
        __syncthreads();                // drain: buf cur^1 ready, cur free
    }
    #undef STAGE1

    // epilogue: silu(z1)*z3 -> bf16
    #pragma unroll
    for (int fm = 0; fm < 2; ++fm) {
        #pragma unroll
        for (int fn = 0; fn < 2; ++fn) {
            const int col = itile*BN + wn*32 + fn*16 + l15;
            const float bv1 = B1[col];
            const float bv3 = B3[col];
            #pragma unroll
            for (int j = 0; j < 4; ++j) {
                const int rl = wm*32 + fm*16 + lg*4 + j;   // C/D: row=(lane>>4)*4+reg, col=lane&15
                if (rl < rows) {
                    float z1 = acc1[fm][fn][j] + bv1;
                    float z3 = acc3[fm][fn][j] + bv3;
                    float h = z1 / (1.f + __expf(-z1)) * z3;
                    h1buf[(size_t)(off+ro+rl)*I_ + col] = f2bf(h);
                }
            }
        }
    }
}

// ---------------------------------------------------------------------------
// Stage 2: y = gate * (h1 @ w2^T + b2) -> fp32
// Same gload_lds structure. h1 already bf16 (direct), w2 fp32-in-LDS.
// LDS = 64KB -> 2 blocks/CU.
// ---------------------------------------------------------------------------
__global__ __launch_bounds__(512, 4) void moe_stage2(
    const ushort* __restrict__ h1buf,
    const float* __restrict__ w2, const float* __restrict__ b2,
    const float* __restrict__ sw2, const float* __restrict__ sb2,
    const int* __restrict__ cnts, const int* __restrict__ offs,
    const float* __restrict__ entry_gate,
    const int* __restrict__ blk_e, const int* __restrict__ blk_ro,
    const int* __restrict__ nwork,
    float* __restrict__ ybuf)
{
    const int w = blockIdx.x;
    if (w >= nwork[0]) return;
    const int e  = blk_e[w];
    const int ro = blk_ro[w];
    const int htile = blockIdx.y;   // 0..H_/BN-1
    const int n = cnts[e];
    const int off = offs[e];
    const int rows = min(BM, n - ro);
    const float* W2 = (e < E_) ? (w2 + (size_t)e*H_*I_) : sw2;
    const float* B2 = (e < E_) ? (b2 + (size_t)e*H_) : sb2;

    __shared__ ushort HL[2][BM*BKS];     // 2 x 16KB
    __shared__ float  W2L[2][BN*BKS];    // 2 x 16KB

    const int tid  = threadIdx.x;
    const int lane = tid & 63;
    const int wid  = tid >> 6;          // 0..7
    const int wm   = wid >> 1;
    const int wn   = wid & 1;
    const int l15  = lane & 15;
    const int lg   = lane >> 4;

    // H: 16 issues of 1KB; wave handles j = wid*2 + i (rows contiguous entries)
    const ushort* hsrc[2];
    #pragma unroll
    for (int i = 0; i < 2; ++i) {
        const int j = wid*2 + i;
        const int r = j*8 + (lane >> 3);
        const int csw = ((lane & 7) ^ (r & 7)) << 3;
        hsrc[i] = h1buf + (size_t)(off + ro + r)*I_ + csw;
    }
    // W2: 16 issues of 1KB (4 rows x 256B); wave handles j = wid*2 + i.
    const float* w2src[2];
    #pragma unroll
    for (int i = 0; i < 2; ++i) {
        const int j = wid*2 + i;
        const int rb = j*4 + (lane >> 4);          // 0..63
        const int c16 = lane & 15;
        const int csw = ((((c16 >> 1) ^ (rb & 7)) << 3) + ((c16 & 1) << 2));
        w2src[i] = W2 + (size_t)(htile*BN + rb)*I_ + csw;
    }

    f32x4 acc[2][2] = {};

    #define STAGE2(t, buf)                                                        \
        do {                                                                      \
            const int kc_ = (t) * BKS;                                            \
            _Pragma("unroll")                                                     \
            for (int i_ = 0; i_ < 2; ++i_)                                        \
                gload16(hsrc[i_] + kc_, (char*)&HL[buf][0] + (wid*2 + i_)*1024);  \
            _Pragma("unroll")                                                     \
            for (int i_ = 0; i_ < 2; ++i_)                                        \
                gload16(w2src[i_] + kc_, (char*)&W2L[buf][0] + (wid*2 + i_)*1024);\
        } while (0)

    STAGE2(0, 0);
    __syncthreads();

    const int NT = I_ / BKS;            // 16
    for (int t = 0; t < NT; ++t) {
        const int cur = t & 1;
        if (t + 1 < NT) STAGE2(t + 1, cur ^ 1);
        asm volatile("" ::: "memory");
        #pragma unroll
        for (int s = 0; s < 2; ++s) {
            bf16x8 a[2], b[2];
            #pragma unroll
            for (int f = 0; f < 2; ++f) {
                const int rr = wm*32 + f*16 + l15;
                a[f] = *reinterpret_cast<const bf16x8*>(
                    (const char*)&HL[cur][0] + rr*128 + ((((s<<2)|lg) ^ (rr&7)) << 4));
                const int rw = wn*32 + f*16 + l15;
                const char* p = (const char*)&W2L[cur][0] + rw*256
                              + ((((s<<2)|lg) ^ (rw&7)) << 5);
                f32x4 u0 = *reinterpret_cast<const f32x4*>(p);
                f32x4 u1 = *reinterpret_cast<const f32x4*>(p + 16);
                b[f] = cvt8(u0, u1);
            }
            #pragma unroll
            for (int fm = 0; fm < 2; ++fm) {
                #pragma unroll
                for (int fn = 0; fn < 2; ++fn) {
                    acc[fm][fn] = __builtin_amdgcn_mfma_f32_16x16x32_bf16(a[fm], b[fn], acc[fm][fn], 0, 0, 0);
                }
            }
        }
        __syncthreads();
    }
    #undef STAGE2

    #pragma unroll
    for (int fm = 0; fm < 2; ++fm) {
        #pragma unroll
        for (int fn = 0; fn < 2; ++fn) {
            const int col = htile*BN + wn*32 + fn*16 + l15;
            const float bv = B2[col];
            #pragma unroll
            for (int j = 0; j < 4; ++j) {
                const int rl = wm*32 + fm*16 + lg*4 + j;
                if (rl < rows) {
                    const float g = entry_gate[off + ro + rl];
                    ybuf[(size_t)(off+ro+rl)*H_ + col] = (acc[fm][fn][j] + bv) * g;
                }
            }
        }
    }
}

// ---------------------------------------------------------------------------
// Combine: out[t] = y_shared[t] + sum_k y_routed[pair_pos[t,k]]
// ---------------------------------------------------------------------------
__global__ __launch_bounds__(128) void moe_combine(
    const float* __restrict__ ybuf, const int* __restrict__ pair_pos,
    float* __restrict__ out)
{
    const int t = blockIdx.x;
    const int lane = threadIdx.x;     // 128 threads * 4 floats = 512
    const int h = lane * 4;
    const int p0 = pair_pos[t*K_+0], p1 = pair_pos[t*K_+1];
    const int p2 = pair_pos[t*K_+2], p3 = pair_pos[t*K_+3];
    float4 a  = *reinterpret_cast<const float4*>(ybuf + (size_t)(NPAIR+t)*H_ + h);
    float4 v0 = *reinterpret_cast<const float4*>(ybuf + (size_t)p0*H_ + h);
    float4 v1 = *reinterpret_cast<const float4*>(ybuf + (size_t)p1*H_ + h);
    float4 v2 = *reinterpret_cast<const float4*>(ybuf + (size_t)p2*H_ + h);
    float4 v3 = *reinterpret_cast<const float4*>(ybuf + (size_t)p3*H_ + h);
    float4 r;
    r.x = a.x + v0.x + v1.x + v2.x + v3.x;
    r.y = a.y + v0.y + v1.y + v2.y + v3.y;
    r.z = a.z + v0.z + v1.z + v2.z + v3.z;
    r.w = a.w + v0.w + v1.w + v2.w + v3.w;
    *reinterpret_cast<float4*>(out + (size_t)t*H_ + h) = r;
}

extern "C" void kernel_launch(void* const* d_in, const int* in_sizes, int n_in,
                              void* d_out, int out_size, void* d_ws, size_t ws_size,
                              hipStream_t stream)
{
    const float* x   = (const float*)d_in[0];
    const float* rw  = (const float*)d_in[1];
    const float* rb  = (const float*)d_in[2];
    const float* eb  = (const float*)d_in[3];
    const float* sw1 = (const float*)d_in[4];
    const float* sb1 = (const float*)d_in[5];
    const float* sw2 = (const float*)d_in[6];
    const float* sb2 = (const float*)d_in[7];
    const float* sw3 = (const float*)d_in[8];
    const float* sb3 = (const float*)d_in[9];
    const float* w1  = (const float*)d_in[10];
    const float* b1  = (const float*)d_in[11];
    const float* w2  = (const float*)d_in[12];
    const float* b2  = (const float*)d_in[13];
    const float* w3  = (const float*)d_in[14];
    const float* b3  = (const float*)d_in[15];
    float* out = (float*)d_out;

    char* p = (char*)d_ws;
    auto take = [&](size_t bytes) { char* q = p; p += (bytes + 255) & ~(size_t)255; return q; };
    int*    idxb  = (int*)   take((size_t)NPAIR*4);
    float*  gateb = (float*) take((size_t)NPAIR*4);
    int*    cnts  = (int*)   take((E_+1)*4);
    int*    offs  = (int*)   take((E_+1)*4);
    int*    etok  = (int*)   take((size_t)NENT*4);
    float*  egate = (float*) take((size_t)NENT*4);
    int*    ppos  = (int*)   take((size_t)NPAIR*4);
    int*    blk_e = (int*)   take((size_t)MAXWORK*4);
    int*    blk_ro= (int*)   take((size_t)MAXWORK*4);
    int*    nwork = (int*)   take(4);
    ushort* xbf   = (ushort*)take((size_t)T_*H_*2);
    ushort* h1buf = (ushort*)take((size_t)NENT*I_*2);
    float*  ybuf  = (float*) take((size_t)NENT*H_*4);

    x_cvt      <<<(T_*H_)/(256*4), 256, 0, stream>>>(x, xbf);
    moe_router <<<T_, 64, 0, stream>>>(x, rw, rb, eb, idxb, gateb);
    moe_build  <<<1, 256, 0, stream>>>(idxb, gateb, cnts, offs, etok, egate, ppos,
                                       blk_e, blk_ro, nwork);
    moe_stage1 <<<dim3(MAXWORK, I_/BN), 512, 0, stream>>>(xbf, w1, b1, w3, b3,
                                                          sw1, sb1, sw3, sb3,
                                                          cnts, offs, etok,
                                                          blk_e, blk_ro, nwork, h1buf);
    moe_stage2 <<<dim3(MAXWORK, H_/BN), 512, 0, stream>>>(h1buf, w2, b2, sw2, sb2,
                                                          cnts, offs, egate,
                                                          blk_e, blk_ro, nwork, ybuf);
    moe_combine<<<T_, 128, 0, stream>>>(ybuf, ppos, out);
}

// Round 4
// 232.242 us; speedup vs baseline: 1.0521x; 1.0521x over previous
//
#include <hip/hip_runtime.h>
#include <math.h>

// Problem constants (fixed by the reference)
#define T_    1024      // B*S tokens
#define H_    512       // hidden
#define I_    1024      // intermediate
#define E_    64        // routed experts
#define K_    4         // top-k
#define NPAIR (T_*K_)   // 4096 routed (token,slot) pairs
#define NENT  (NPAIR + T_)  // + shared-expert entries at [NPAIR + t]

#define BM 128          // rows per work block
#define BN 64
#define BKS 64          // k-step (elements)
#define LDP 72          // padded LDS row (elements)
#define MAXWORK 160     // worst-case row-blocks: <=96 routed + 8 shared
#define NT1 (H_/BKS)    // 8
#define NT2 (I_/BKS)    // 16

typedef float  f32x4  __attribute__((ext_vector_type(4)));
typedef short  bf16x8 __attribute__((ext_vector_type(8)));

// Raw barrier WITHOUT the __syncthreads() vmcnt(0) drain: LDS ops flushed,
// outstanding global loads stay in flight across the barrier. The compiler
// still emits counted vmcnt waits at the actual register uses.
#define BARRIER() asm volatile("s_waitcnt lgkmcnt(0)\n\ts_barrier" ::: "memory")

__device__ __forceinline__ ushort f2bf(float f) {
    uint u = __float_as_uint(f);
    u += 0x7fffu + ((u >> 16) & 1u);   // round-to-nearest-even
    return (ushort)(u >> 16);
}
__device__ __forceinline__ ushort4 cvt4(float4 v) {
    return make_ushort4(f2bf(v.x), f2bf(v.y), f2bf(v.z), f2bf(v.w));
}

// ---------------------------------------------------------------------------
// Router: one 64-thread block per token.
// ---------------------------------------------------------------------------
__global__ __launch_bounds__(64) void moe_router(
    const float* __restrict__ x, const float* __restrict__ rw,
    const float* __restrict__ rb, const float* __restrict__ eb,
    int* __restrict__ idx_out, float* __restrict__ gate_out)
{
    const int t = blockIdx.x;
    const int lane = threadIdx.x;  // 0..63
    __shared__ float xs[H_];
    __shared__ float lg[E_];
    __shared__ float bs[E_];
    for (int i = lane; i < H_; i += 64) xs[i] = x[(size_t)t*H_ + i];
    bs[lane] = eb[lane];
    __syncthreads();
    float acc = 0.f;
    const float* wrow = rw + (size_t)lane*H_;
    for (int k = 0; k < H_; k += 4) {
        float4 w4 = *reinterpret_cast<const float4*>(wrow + k);
        acc = fmaf(xs[k+0], w4.x, acc);
        acc = fmaf(xs[k+1], w4.y, acc);
        acc = fmaf(xs[k+2], w4.z, acc);
        acc = fmaf(xs[k+3], w4.w, acc);
    }
    lg[lane] = acc + rb[lane];
    __syncthreads();
    if (lane == 0) {
        unsigned long long used = 0ull;
        int sel[K_]; float orig[K_];
        for (int k = 0; k < K_; ++k) {
            float best = -INFINITY; int bi = 0;
            for (int e = 0; e < E_; ++e) {
                if (used & (1ull << e)) continue;
                float v = lg[e] + bs[e];
                if (v > best) { best = v; bi = e; }   // strict > : lowest idx on tie
            }
            used |= (1ull << bi);
            sel[k] = bi; orig[k] = lg[bi];
        }
        float s[K_]; float sum = 0.f;
        for (int k = 0; k < K_; ++k) { s[k] = 1.f/(1.f + __expf(-orig[k])); sum += s[k]; }
        sum = fmaxf(sum, 1e-12f);
        for (int k = 0; k < K_; ++k) {
            idx_out[t*K_ + k] = sel[k];
            gate_out[t*K_ + k] = s[k] / sum;
        }
    }
}

// ---------------------------------------------------------------------------
// Build per-expert token lists + flattened row-block work list (single block).
// ---------------------------------------------------------------------------
__global__ __launch_bounds__(256) void moe_build(
    const int* __restrict__ idx, const float* __restrict__ gates,
    int* __restrict__ cnts, int* __restrict__ offs,
    int* __restrict__ entry_token, float* __restrict__ entry_gate,
    int* __restrict__ pair_pos,
    int* __restrict__ blk_e, int* __restrict__ blk_ro, int* __restrict__ nwork)
{
    __shared__ int c[E_];
    __shared__ int run[E_];
    const int tid = threadIdx.x;
    if (tid < E_) c[tid] = 0;
    __syncthreads();
    for (int p = tid; p < NPAIR; p += 256) atomicAdd(&c[idx[p]], 1);
    __syncthreads();
    if (tid == 0) {
        int o = 0;
        for (int e = 0; e < E_; ++e) { run[e] = o; offs[e] = o; cnts[e] = c[e]; o += c[e]; }
        offs[E_] = NPAIR;   // shared-expert entries
        cnts[E_] = T_;
        int nb = 0;
        for (int e = 0; e <= E_; ++e) {
            int n = (e < E_) ? c[e] : T_;
            for (int ro = 0; ro < n; ro += BM) { blk_e[nb] = e; blk_ro[nb] = ro; ++nb; }
        }
        nwork[0] = nb;
    }
    __syncthreads();
    for (int p = tid; p < NPAIR; p += 256) {
        int e = idx[p];
        int pos = atomicAdd(&run[e], 1);
        entry_token[pos] = p / K_;
        entry_gate[pos]  = gates[p];
        pair_pos[p]      = pos;
    }
    for (int t = tid; t < T_; t += 256) {
        entry_token[NPAIR + t] = t;
        entry_gate[NPAIR + t]  = 1.0f;
    }
}

// ---------------------------------------------------------------------------
// Stage 1: h1 = silu(X w1^T + b1) * (X w3^T + b3) -> bf16
// 512 thr = 8 waves (4x2 of 32x32). 2-deep register pipeline + LDS dbuf +
// raw barriers (no vmcnt drain): loads for step t+2 issued at step t.
// ---------------------------------------------------------------------------
__global__ __launch_bounds__(512, 4) void moe_stage1(
    const float* __restrict__ x,
    const float* __restrict__ w1, const float* __restrict__ b1,
    const float* __restrict__ w3, const float* __restrict__ b3,
    const float* __restrict__ sw1, const float* __restrict__ sb1,
    const float* __restrict__ sw3, const float* __restrict__ sb3,
    const int* __restrict__ cnts, const int* __restrict__ offs,
    const int* __restrict__ entry_token,
    const int* __restrict__ blk_e, const int* __restrict__ blk_ro,
    const int* __restrict__ nwork,
    ushort* __restrict__ h1buf)
{
    const int w = blockIdx.x;
    if (w >= nwork[0]) return;
    const int e  = blk_e[w];
    const int ro = blk_ro[w];
    const int itile = blockIdx.y;   // 0..I_/BN-1
    const int n = cnts[e];
    const int off = offs[e];
    const int rows = min(BM, n - ro);
    const float* W1 = (e < E_) ? (w1 + (size_t)e*I_*H_) : sw1;
    const float* W3 = (e < E_) ? (w3 + (size_t)e*I_*H_) : sw3;
    const float* B1 = (e < E_) ? (b1 + (size_t)e*I_) : sb1;
    const float* B3 = (e < E_) ? (b3 + (size_t)e*I_) : sb3;

    __shared__ ushort Xs [2][BM][LDP];   // 36864 B
    __shared__ ushort W1s[2][BN][LDP];   // 18432 B
    __shared__ ushort W3s[2][BN][LDP];   // 18432 B

    const int tid  = threadIdx.x;
    const int lane = tid & 63;
    const int wid  = tid >> 6;          // 0..7
    const int wm   = wid >> 1;          // 0..3
    const int wn   = wid & 1;           // 0..1
    const int l15  = lane & 15;
    const int lg   = lane >> 4;         // 0..3

    const int sr = tid >> 4;            // staging row base 0..31
    const int sc = tid & 15;            // 16B column chunk 0..15

    // K-invariant row pointers. Rows beyond 'rows' read a neighboring valid
    // entry (all NENT entries initialized); garbage lands only in masked rows.
    const float* xp[4];
    #pragma unroll
    for (int i = 0; i < 4; ++i)
        xp[i] = x + (size_t)entry_token[off + ro + sr + i*32]*H_ + sc*4;
    const float* wp[2];
    #pragma unroll
    for (int i = 0; i < 2; ++i)
        wp[i] = W1 + (size_t)(itile*BN + sr + i*32)*H_ + sc*4;
    const ptrdiff_t d31 = (const float*)W3 - (const float*)W1;

    f32x4 acc1[2][2] = {};
    f32x4 acc3[2][2] = {};

    float4 A[8], B[8];   // two named pipeline sets (static indexing only)

    auto issue = [&](float4* R, int kc) {
        #pragma unroll
        for (int i = 0; i < 4; ++i) R[i] = *reinterpret_cast<const float4*>(xp[i] + kc);
        #pragma unroll
        for (int i = 0; i < 2; ++i) {
            R[4+i] = *reinterpret_cast<const float4*>(wp[i] + kc);
            R[6+i] = *reinterpret_cast<const float4*>(wp[i] + kc + d31);
        }
    };
    auto cvtwrite = [&](const float4* R, int b) {
        #pragma unroll
        for (int i = 0; i < 4; ++i)
            *reinterpret_cast<ushort4*>(&Xs[b][sr + i*32][sc*4]) = cvt4(R[i]);
        #pragma unroll
        for (int i = 0; i < 2; ++i) {
            *reinterpret_cast<ushort4*>(&W1s[b][sr + i*32][sc*4]) = cvt4(R[4+i]);
            *reinterpret_cast<ushort4*>(&W3s[b][sr + i*32][sc*4]) = cvt4(R[6+i]);
        }
    };
    auto mfma_step = [&](int b) {
        #pragma unroll
        for (int s = 0; s < 2; ++s) {
            bf16x8 a[2], bb1[2], bb3[2];
            #pragma unroll
            for (int f = 0; f < 2; ++f) {
                a[f]   = *reinterpret_cast<const bf16x8*>(&Xs [b][wm*32 + f*16 + l15][s*32 + lg*8]);
                bb1[f] = *reinterpret_cast<const bf16x8*>(&W1s[b][wn*32 + f*16 + l15][s*32 + lg*8]);
                bb3[f] = *reinterpret_cast<const bf16x8*>(&W3s[b][wn*32 + f*16 + l15][s*32 + lg*8]);
            }
            #pragma unroll
            for (int fm = 0; fm < 2; ++fm) {
                #pragma unroll
                for (int fn = 0; fn < 2; ++fn) {
                    acc1[fm][fn] = __builtin_amdgcn_mfma_f32_16x16x32_bf16(a[fm], bb1[fn], acc1[fm][fn], 0, 0, 0);
                    acc3[fm][fn] = __builtin_amdgcn_mfma_f32_16x16x32_bf16(a[fm], bb3[fn], acc3[fm][fn], 0, 0, 0);
                }
            }
        }
    };

    // prologue: fill 2-deep pipeline, stage step 0
    issue(A, 0);
    issue(B, BKS);
    cvtwrite(A, 0);         // counted vmcnt wait for A only; B stays in flight
    BARRIER();

    #pragma unroll
    for (int tt = 0; tt < NT1; tt += 2) {
        // even step tt: compute buf0; prefetch tt+2 -> A; stage tt+1 from B
        mfma_step(0);
        if (tt + 2 < NT1) issue(A, (tt + 2)*BKS);
        cvtwrite(B, 1);
        BARRIER();
        // odd step tt+1: compute buf1; prefetch tt+3 -> B; stage tt+2 from A
        mfma_step(1);
        if (tt + 3 < NT1) issue(B, (tt + 3)*BKS);
        if (tt + 2 < NT1) cvtwrite(A, 0);
        BARRIER();
    }

    // epilogue: silu(z1)*z3 -> bf16
    #pragma unroll
    for (int fm = 0; fm < 2; ++fm) {
        #pragma unroll
        for (int fn = 0; fn < 2; ++fn) {
            const int col = itile*BN + wn*32 + fn*16 + l15;
            const float bv1 = B1[col];
            const float bv3 = B3[col];
            #pragma unroll
            for (int j = 0; j < 4; ++j) {
                const int rl = wm*32 + fm*16 + lg*4 + j;   // C/D: row=(lane>>4)*4+reg, col=lane&15
                if (rl < rows) {
                    float z1 = acc1[fm][fn][j] + bv1;
                    float z3 = acc3[fm][fn][j] + bv3;
                    float h = z1 / (1.f + __expf(-z1)) * z3;
                    h1buf[(size_t)(off+ro+rl)*I_ + col] = f2bf(h);
                }
            }
        }
    }
}

// ---------------------------------------------------------------------------
// Stage 2: y = gate * (h1 @ w2^T + b2) -> fp32. Same pipeline template.
// ---------------------------------------------------------------------------
__global__ __launch_bounds__(512, 4) void moe_stage2(
    const ushort* __restrict__ h1buf,
    const float* __restrict__ w2, const float* __restrict__ b2,
    const float* __restrict__ sw2, const float* __restrict__ sb2,
    const int* __restrict__ cnts, const int* __restrict__ offs,
    const float* __restrict__ entry_gate,
    const int* __restrict__ blk_e, const int* __restrict__ blk_ro,
    const int* __restrict__ nwork,
    float* __restrict__ ybuf)
{
    const int w = blockIdx.x;
    if (w >= nwork[0]) return;
    const int e  = blk_e[w];
    const int ro = blk_ro[w];
    const int htile = blockIdx.y;   // 0..H_/BN-1
    const int n = cnts[e];
    const int off = offs[e];
    const int rows = min(BM, n - ro);
    const float* W2 = (e < E_) ? (w2 + (size_t)e*H_*I_) : sw2;
    const float* B2 = (e < E_) ? (b2 + (size_t)e*H_) : sb2;

    __shared__ ushort Hs[2][BM][LDP];    // 36864 B
    __shared__ ushort Ws[2][BN][LDP];    // 18432 B

    const int tid  = threadIdx.x;
    const int lane = tid & 63;
    const int wid  = tid >> 6;          // 0..7
    const int wm   = wid >> 1;
    const int wn   = wid & 1;
    const int l15  = lane & 15;
    const int lg   = lane >> 4;

    const int sr = tid >> 4;            // 0..31 (weight staging)
    const int sc = tid & 15;
    const int hr = tid >> 3;            // 0..63 (h1 staging)
    const int hc = tid & 7;

    const ushort* hp[2];
    #pragma unroll
    for (int i = 0; i < 2; ++i)
        hp[i] = h1buf + (size_t)(off + ro + hr + i*64)*I_ + hc*8;
    const float* wp[2];
    #pragma unroll
    for (int i = 0; i < 2; ++i)
        wp[i] = W2 + (size_t)(htile*BN + sr + i*32)*I_ + sc*4;

    f32x4 acc[2][2] = {};

    uint4  HA[2], HB[2];
    float4 WA[2], WB[2];

    auto issue = [&](uint4* HR, float4* WR, int kc) {
        #pragma unroll
        for (int i = 0; i < 2; ++i) {
            HR[i] = *reinterpret_cast<const uint4*>(hp[i] + kc);
            WR[i] = *reinterpret_cast<const float4*>(wp[i] + kc);
        }
    };
    auto stwrite = [&](const uint4* HR, const float4* WR, int b) {
        #pragma unroll
        for (int i = 0; i < 2; ++i) {
            *reinterpret_cast<uint4*>(&Hs[b][hr + i*64][hc*8]) = HR[i];
            *reinterpret_cast<ushort4*>(&Ws[b][sr + i*32][sc*4]) = cvt4(WR[i]);
        }
    };
    auto mfma_step = [&](int b) {
        #pragma unroll
        for (int s = 0; s < 2; ++s) {
            bf16x8 a[2], bb[2];
            #pragma unroll
            for (int f = 0; f < 2; ++f) {
                a[f]  = *reinterpret_cast<const bf16x8*>(&Hs[b][wm*32 + f*16 + l15][s*32 + lg*8]);
                bb[f] = *reinterpret_cast<const bf16x8*>(&Ws[b][wn*32 + f*16 + l15][s*32 + lg*8]);
            }
            #pragma unroll
            for (int fm = 0; fm < 2; ++fm) {
                #pragma unroll
                for (int fn = 0; fn < 2; ++fn) {
                    acc[fm][fn] = __builtin_amdgcn_mfma_f32_16x16x32_bf16(a[fm], bb[fn], acc[fm][fn], 0, 0, 0);
                }
            }
        }
    };

    issue(HA, WA, 0);
    issue(HB, WB, BKS);
    stwrite(HA, WA, 0);
    BARRIER();

    #pragma unroll
    for (int tt = 0; tt < NT2; tt += 2) {
        mfma_step(0);
        if (tt + 2 < NT2) issue(HA, WA, (tt + 2)*BKS);
        stwrite(HB, WB, 1);
        BARRIER();
        mfma_step(1);
        if (tt + 3 < NT2) issue(HB, WB, (tt + 3)*BKS);
        if (tt + 2 < NT2) stwrite(HA, WA, 0);
        BARRIER();
    }

    #pragma unroll
    for (int fm = 0; fm < 2; ++fm) {
        #pragma unroll
        for (int fn = 0; fn < 2; ++fn) {
            const int col = htile*BN + wn*32 + fn*16 + l15;
            const float bv = B2[col];
            #pragma unroll
            for (int j = 0; j < 4; ++j) {
                const int rl = wm*32 + fm*16 + lg*4 + j;
                if (rl < rows) {
                    const float g = entry_gate[off + ro + rl];
                    ybuf[(size_t)(off+ro+rl)*H_ + col] = (acc[fm][fn][j] + bv) * g;
                }
            }
        }
    }
}

// ---------------------------------------------------------------------------
// Combine: out[t] = y_shared[t] + sum_k y_routed[pair_pos[t,k]]
// ---------------------------------------------------------------------------
__global__ __launch_bounds__(128) void moe_combine(
    const float* __restrict__ ybuf, const int* __restrict__ pair_pos,
    float* __restrict__ out)
{
    const int t = blockIdx.x;
    const int lane = threadIdx.x;     // 128 threads * 4 floats = 512
    const int h = lane * 4;
    const int p0 = pair_pos[t*K_+0], p1 = pair_pos[t*K_+1];
    const int p2 = pair_pos[t*K_+2], p3 = pair_pos[t*K_+3];
    float4 a  = *reinterpret_cast<const float4*>(ybuf + (size_t)(NPAIR+t)*H_ + h);
    float4 v0 = *reinterpret_cast<const float4*>(ybuf + (size_t)p0*H_ + h);
    float4 v1 = *reinterpret_cast<const float4*>(ybuf + (size_t)p1*H_ + h);
    float4 v2 = *reinterpret_cast<const float4*>(ybuf + (size_t)p2*H_ + h);
    float4 v3 = *reinterpret_cast<const float4*>(ybuf + (size_t)p3*H_ + h);
    float4 r;
    r.x = a.x + v0.x + v1.x + v2.x + v3.x;
    r.y = a.y + v0.y + v1.y + v2.y + v3.y;
    r.z = a.z + v0.z + v1.z + v2.z + v3.z;
    r.w = a.w + v0.w + v1.w + v2.w + v3.w;
    *reinterpret_cast<float4*>(out + (size_t)t*H_ + h) = r;
}

extern "C" void kernel_launch(void* const* d_in, const int* in_sizes, int n_in,
                              void* d_out, int out_size, void* d_ws, size_t ws_size,
                              hipStream_t stream)
{
    const float* x   = (const float*)d_in[0];
    const float* rw  = (const float*)d_in[1];
    const float* rb  = (const float*)d_in[2];
    const float* eb  = (const float*)d_in[3];
    const float* sw1 = (const float*)d_in[4];
    const float* sb1 = (const float*)d_in[5];
    const float* sw2 = (const float*)d_in[6];
    const float* sb2 = (const float*)d_in[7];
    const float* sw3 = (const float*)d_in[8];
    const float* sb3 = (const float*)d_in[9];
    const float* w1  = (const float*)d_in[10];
    const float* b1  = (const float*)d_in[11];
    const float* w2  = (const float*)d_in[12];
    const float* b2  = (const float*)d_in[13];
    const float* w3  = (const float*)d_in[14];
    const float* b3  = (const float*)d_in[15];
    float* out = (float*)d_out;

    char* p = (char*)d_ws;
    auto take = [&](size_t bytes) { char* q = p; p += (bytes + 255) & ~(size_t)255; return q; };
    int*    idxb  = (int*)   take((size_t)NPAIR*4);
    float*  gateb = (float*) take((size_t)NPAIR*4);
    int*    cnts  = (int*)   take((E_+1)*4);
    int*    offs  = (int*)   take((E_+1)*4);
    int*    etok  = (int*)   take((size_t)NENT*4);
    float*  egate = (float*) take((size_t)NENT*4);
    int*    ppos  = (int*)   take((size_t)NPAIR*4);
    int*    blk_e = (int*)   take((size_t)MAXWORK*4);
    int*    blk_ro= (int*)   take((size_t)MAXWORK*4);
    int*    nwork = (int*)   take(4);
    ushort* h1buf = (ushort*)take((size_t)NENT*I_*2);
    float*  ybuf  = (float*) take((size_t)NENT*H_*4);

    moe_router <<<T_, 64, 0, stream>>>(x, rw, rb, eb, idxb, gateb);
    moe_build  <<<1, 256, 0, stream>>>(idxb, gateb, cnts, offs, etok, egate, ppos,
                                       blk_e, blk_ro, nwork);
    moe_stage1 <<<dim3(MAXWORK, I_/BN), 512, 0, stream>>>(x, w1, b1, w3, b3,
                                                          sw1, sb1, sw3, sb3,
                                                          cnts, offs, etok,
                                                          blk_e, blk_ro, nwork, h1buf);
    moe_stage2 <<<dim3(MAXWORK, H_/BN), 512, 0, stream>>>(h1buf, w2, b2, sw2, sb2,
                                                          cnts, offs, egate,
                                                          blk_e, blk_ro, nwork, ybuf);
    moe_combine<<<T_, 128, 0, stream>>>(ybuf, ppos, out);
}